// Round 2
// baseline (695.499 us; speedup 1.0000x reference)
//
#include <hip/hip_runtime.h>
#include <hip/hip_bf16.h>

#define IN_D 128
#define HID_D 128
#define OUT_DD 64
#define BN_EPS 1e-5f

// ---------------- CSR build ----------------
// edge_index is staged as int32 by the harness (JAX int64 w/o x64 -> int32;
// harness rule: "integer -> const int*"). Layout: row0 = src[E], row1 = dst[E].

__global__ void k_hist(const int* __restrict__ ei, int* __restrict__ deg, int E, int n) {
    int e = blockIdx.x * 256 + threadIdx.x;
    if (e < E) {
        int dst = ei[E + e];
        if (dst >= 0 && dst < n) atomicAdd(&deg[dst], 1);
    }
}

__global__ void k_block_sum(const int* __restrict__ deg, int* __restrict__ bsum, int n) {
    __shared__ int sdata[256];
    int i = blockIdx.x * 256 + threadIdx.x;
    int v = (i < n) ? deg[i] : 0;
    sdata[threadIdx.x] = v;
    __syncthreads();
    for (int s = 128; s > 0; s >>= 1) {
        if (threadIdx.x < s) sdata[threadIdx.x] += sdata[threadIdx.x + s];
        __syncthreads();
    }
    if (threadIdx.x == 0) bsum[blockIdx.x] = sdata[0];
}

// exclusive scan of bsum[nb], nb <= 256, single block of 256 threads
__global__ void k_scan_bsum(int* __restrict__ bsum, int nb) {
    __shared__ int s[256];
    int t = threadIdx.x;
    int v = (t < nb) ? bsum[t] : 0;
    s[t] = v;
    __syncthreads();
    for (int off = 1; off < 256; off <<= 1) {
        int u = (t >= off) ? s[t - off] : 0;
        __syncthreads();
        s[t] += u;
        __syncthreads();
    }
    if (t < nb) bsum[t] = s[t] - v;  // exclusive
}

__global__ void k_scan_deg(const int* __restrict__ deg, const int* __restrict__ boff,
                           int* __restrict__ rowptr, int* __restrict__ cursor,
                           float* __restrict__ invcnt, int n) {
    __shared__ int s[256];
    int t = threadIdx.x;
    int i = blockIdx.x * 256 + t;
    int v = (i < n) ? deg[i] : 0;
    s[t] = v;
    __syncthreads();
    for (int off = 1; off < 256; off <<= 1) {
        int u = (t >= off) ? s[t - off] : 0;
        __syncthreads();
        s[t] += u;
        __syncthreads();
    }
    int incl = s[t];
    int excl = incl - v;
    int base = boff[blockIdx.x];
    if (i < n) {
        rowptr[i] = base + excl;
        cursor[i] = base + excl;
        invcnt[i] = 1.0f / (float)(v < 1 ? 1 : v);
        if (i == n - 1) rowptr[n] = base + incl;
    }
}

__global__ void k_fill(const int* __restrict__ ei, const float* __restrict__ ew,
                       int* __restrict__ cursor, int* __restrict__ csr_src,
                       float* __restrict__ csr_w, int E, int n) {
    int e = blockIdx.x * 256 + threadIdx.x;
    if (e < E) {
        int dst = ei[E + e];
        int src = ei[e];
        if (dst < 0 || dst >= n) return;
        if (src < 0) src = 0;
        if (src >= n) src = n - 1;
        int slot = atomicAdd(&cursor[dst], 1);
        csr_src[slot] = src;
        csr_w[slot] = ew[e];
    }
}

// ---------------- aggregation: mean_i = (1/cnt) * sum_j w_ij * x_j ----------------
// one wave (64 lanes) per node; lane owns dims 2l,2l+1 (float2 -> 512B coalesced row read)
__global__ void k_agg(const float* __restrict__ X, const int* __restrict__ rowptr,
                      const int* __restrict__ csr_src, const float* __restrict__ csr_w,
                      const float* __restrict__ invcnt, float* __restrict__ M, int n) {
    int wid = (blockIdx.x * blockDim.x + threadIdx.x) >> 6;  // node id
    int lane = threadIdx.x & 63;
    if (wid >= n) return;
    int beg = rowptr[wid];
    int end = rowptr[wid + 1];
    const float2* X2 = (const float2*)X;
    float ax = 0.f, ay = 0.f;
    for (int k = beg; k < end; ++k) {
        int s = csr_src[k];
        float w = csr_w[k];
        float2 v = X2[(size_t)s * 64 + lane];
        ax += w * v.x;
        ay += w * v.y;
    }
    float ic = invcnt[wid];
    float2 m;
    m.x = ax * ic;
    m.y = ay * ic;
    ((float2*)M)[(size_t)wid * 64 + lane] = m;
}

// ---------------- fused GEMM + bias + BN + LeakyReLU ----------------
// out[i][j] = sum_k M[i][k]*Wl[j][k] + b[j] + sum_k X[i][k]*Wr[j][k]
// block = 64 threads (1 wave), 16 nodes per block, thread owns col j = t (+64 if D_OUT=128)
template <int D_OUT, bool BN>
__global__ __launch_bounds__(64) void k_gemm(
    const float* __restrict__ M, const float* __restrict__ X,
    const float* __restrict__ Wl, const float* __restrict__ bias,
    const float* __restrict__ Wr,
    const float* __restrict__ bng, const float* __restrict__ bnb,
    const float* __restrict__ bnm, const float* __restrict__ bnv,
    float* __restrict__ Out, int n) {
    __shared__ float sM[16 * 128];
    __shared__ float sX[16 * 128];
    int t = threadIdx.x;
    int node0 = blockIdx.x * 16;

    const float4* M4 = (const float4*)(M + (size_t)node0 * 128);
    const float4* X4 = (const float4*)(X + (size_t)node0 * 128);
    float4* sM4 = (float4*)sM;
    float4* sX4 = (float4*)sX;
#pragma unroll
    for (int r = 0; r < 8; ++r) {  // 16*128 floats = 512 float4 / 64 threads
        sM4[r * 64 + t] = M4[r * 64 + t];
        sX4[r * 64 + t] = X4[r * 64 + t];
    }
    __syncthreads();

    constexpr int NJ = D_OUT / 64;
    float acc[16][NJ];
#pragma unroll
    for (int i = 0; i < 16; ++i)
#pragma unroll
        for (int jj = 0; jj < NJ; ++jj) acc[i][jj] = 0.f;

    for (int k4 = 0; k4 < 32; ++k4) {
        float4 wl[NJ], wr[NJ];
#pragma unroll
        for (int jj = 0; jj < NJ; ++jj) {
            int j = t + jj * 64;
            wl[jj] = ((const float4*)(Wl + (size_t)j * 128))[k4];
            wr[jj] = ((const float4*)(Wr + (size_t)j * 128))[k4];
        }
#pragma unroll
        for (int i = 0; i < 16; ++i) {
            float4 m4 = sM4[i * 32 + k4];
            float4 x4 = sX4[i * 32 + k4];
#pragma unroll
            for (int jj = 0; jj < NJ; ++jj) {
                acc[i][jj] += m4.x * wl[jj].x + m4.y * wl[jj].y + m4.z * wl[jj].z +
                              m4.w * wl[jj].w + x4.x * wr[jj].x + x4.y * wr[jj].y +
                              x4.z * wr[jj].z + x4.w * wr[jj].w;
            }
        }
    }

#pragma unroll
    for (int jj = 0; jj < NJ; ++jj) {
        int j = t + jj * 64;
        float bj = bias[j];
        float g = 0.f, bb = 0.f, mm = 0.f, iv = 0.f;
        if constexpr (BN) {
            g = bng[j];
            bb = bnb[j];
            mm = bnm[j];
            iv = rsqrtf(bnv[j] + BN_EPS);
        }
#pragma unroll
        for (int i = 0; i < 16; ++i) {
            float h = acc[i][jj] + bj;
            if constexpr (BN) {
                h = (h - mm) * (g * iv) + bb;
                h = h >= 0.f ? h : 0.1f * h;
            }
            Out[(size_t)(node0 + i) * D_OUT + j] = h;
        }
    }
}

// ---------------- row L2 normalize (D=64), one wave per node ----------------
__global__ void k_norm(float* __restrict__ Out, int n) {
    int wid = (blockIdx.x * blockDim.x + threadIdx.x) >> 6;
    int lane = threadIdx.x & 63;
    if (wid >= n) return;
    float v = Out[(size_t)wid * 64 + lane];
    float ss = v * v;
#pragma unroll
    for (int o = 32; o >= 1; o >>= 1) ss += __shfl_xor(ss, o, 64);
    float sc = 1.0f / fmaxf(sqrtf(ss), 1e-12f);
    Out[(size_t)wid * 64 + lane] = v * sc;
}

// ---------------- launch ----------------

extern "C" void kernel_launch(void* const* d_in, const int* in_sizes, int n_in,
                              void* d_out, int out_size, void* d_ws, size_t ws_size,
                              hipStream_t stream) {
    const float* x = (const float*)d_in[0];
    const int* ei = (const int*)d_in[1];      // int32! (harness integer staging)
    const float* ew = (const float*)d_in[2];
    const float* W1l = (const float*)d_in[3];
    const float* b1 = (const float*)d_in[4];
    const float* W1r = (const float*)d_in[5];
    const float* W2l = (const float*)d_in[6];
    const float* b2 = (const float*)d_in[7];
    const float* W2r = (const float*)d_in[8];
    const float* W3l = (const float*)d_in[9];
    const float* b3 = (const float*)d_in[10];
    const float* W3r = (const float*)d_in[11];
    const float* bn1_g = (const float*)d_in[12];
    const float* bn1_b = (const float*)d_in[13];
    const float* bn1_m = (const float*)d_in[14];
    const float* bn1_v = (const float*)d_in[15];
    const float* bn2_g = (const float*)d_in[16];
    const float* bn2_b = (const float*)d_in[17];
    const float* bn2_m = (const float*)d_in[18];
    const float* bn2_v = (const float*)d_in[19];

    const int N = in_sizes[0] / IN_D;   // 50000
    const int E = in_sizes[2];          // 800000
    float* out = (float*)d_out;

    // workspace carve-up (≈84 MB)
    char* p = (char*)d_ws;
    auto alloc = [&](size_t bytes) -> void* {
        void* r = (void*)p;
        p += (bytes + 255) & ~(size_t)255;
        return r;
    };
    int* deg = (int*)alloc((size_t)N * 4);
    int* rowptr = (int*)alloc((size_t)(N + 1) * 4);
    int* cursor = (int*)alloc((size_t)N * 4);
    float* invcnt = (float*)alloc((size_t)N * 4);
    int* bsum = (int*)alloc(256 * 4);
    int* csr_src = (int*)alloc((size_t)E * 4);
    float* csr_w = (float*)alloc((size_t)E * 4);
    float* Mbuf = (float*)alloc((size_t)N * 128 * 4);
    float* H1 = (float*)alloc((size_t)N * 128 * 4);
    float* H2 = (float*)alloc((size_t)N * 128 * 4);

    const int NB = (N + 255) / 256;        // 196 blocks for N-sized scans
    const int EB = (E + 255) / 256;        // 3125 blocks for E-sized kernels
    const int AGG_B = (N + 3) / 4;         // 4 nodes per 256-thread block
    const int GEMM_B = N / 16;             // 16 nodes per 64-thread block

    // --- CSR build (once; reused by all 3 layers) ---
    hipMemsetAsync(deg, 0, (size_t)N * 4, stream);
    k_hist<<<EB, 256, 0, stream>>>(ei, deg, E, N);
    k_block_sum<<<NB, 256, 0, stream>>>(deg, bsum, N);
    k_scan_bsum<<<1, 256, 0, stream>>>(bsum, NB);
    k_scan_deg<<<NB, 256, 0, stream>>>(deg, bsum, rowptr, cursor, invcnt, N);
    k_fill<<<EB, 256, 0, stream>>>(ei, ew, cursor, csr_src, csr_w, E, N);

    // --- layer 1: x -> H1 ---
    k_agg<<<AGG_B, 256, 0, stream>>>(x, rowptr, csr_src, csr_w, invcnt, Mbuf, N);
    k_gemm<128, true><<<GEMM_B, 64, 0, stream>>>(Mbuf, x, W1l, b1, W1r, bn1_g, bn1_b,
                                                 bn1_m, bn1_v, H1, N);
    // --- layer 2: H1 -> H2 ---
    k_agg<<<AGG_B, 256, 0, stream>>>(H1, rowptr, csr_src, csr_w, invcnt, Mbuf, N);
    k_gemm<128, true><<<GEMM_B, 64, 0, stream>>>(Mbuf, H1, W2l, b2, W2r, bn2_g, bn2_b,
                                                 bn2_m, bn2_v, H2, N);
    // --- layer 3: H2 -> out (no BN/act), then L2 normalize ---
    k_agg<<<AGG_B, 256, 0, stream>>>(H2, rowptr, csr_src, csr_w, invcnt, Mbuf, N);
    k_gemm<64, false><<<GEMM_B, 64, 0, stream>>>(Mbuf, H2, W3l, b3, W3r, nullptr, nullptr,
                                                 nullptr, nullptr, out, N);
    k_norm<<<AGG_B, 256, 0, stream>>>(out, N);
}

// Round 6
// 614.097 us; speedup vs baseline: 1.1326x; 1.1326x over previous
//
#include <hip/hip_runtime.h>
#include <hip/hip_bf16.h>

#define IN_D 128
#define BN_EPS 1e-5f

// ---------------- CSR build ----------------
// edge_index staged as int32 (harness integer rule). row0 = src[E], row1 = dst[E].

__global__ void k_hist(const int* __restrict__ ei, int* __restrict__ deg, int E, int n) {
    int e = blockIdx.x * 256 + threadIdx.x;
    if (e < E) {
        int dst = ei[E + e];
        if (dst >= 0 && dst < n) atomicAdd(&deg[dst], 1);
    }
}

__global__ void k_block_sum(const int* __restrict__ deg, int* __restrict__ bsum, int n) {
    __shared__ int sdata[256];
    int i = blockIdx.x * 256 + threadIdx.x;
    int v = (i < n) ? deg[i] : 0;
    sdata[threadIdx.x] = v;
    __syncthreads();
    for (int s = 128; s > 0; s >>= 1) {
        if (threadIdx.x < s) sdata[threadIdx.x] += sdata[threadIdx.x + s];
        __syncthreads();
    }
    if (threadIdx.x == 0) bsum[blockIdx.x] = sdata[0];
}

__global__ void k_scan_bsum(int* __restrict__ bsum, int nb) {
    __shared__ int s[256];
    int t = threadIdx.x;
    int v = (t < nb) ? bsum[t] : 0;
    s[t] = v;
    __syncthreads();
    for (int off = 1; off < 256; off <<= 1) {
        int u = (t >= off) ? s[t - off] : 0;
        __syncthreads();
        s[t] += u;
        __syncthreads();
    }
    if (t < nb) bsum[t] = s[t] - v;  // exclusive
}

__global__ void k_scan_deg(const int* __restrict__ deg, const int* __restrict__ boff,
                           int* __restrict__ rowptr, int* __restrict__ cursor,
                           float* __restrict__ invcnt, int n) {
    __shared__ int s[256];
    int t = threadIdx.x;
    int i = blockIdx.x * 256 + t;
    int v = (i < n) ? deg[i] : 0;
    s[t] = v;
    __syncthreads();
    for (int off = 1; off < 256; off <<= 1) {
        int u = (t >= off) ? s[t - off] : 0;
        __syncthreads();
        s[t] += u;
        __syncthreads();
    }
    int incl = s[t];
    int excl = incl - v;
    int base = boff[blockIdx.x];
    if (i < n) {
        rowptr[i] = base + excl;
        cursor[i] = base + excl;
        invcnt[i] = 1.0f / (float)(v < 1 ? 1 : v);
        if (i == n - 1) rowptr[n] = base + incl;
    }
}

// csr entry packed: .x = src node, .y = edge weight bits
__global__ void k_fill(const int* __restrict__ ei, const float* __restrict__ ew,
                       int* __restrict__ cursor, int2* __restrict__ csr, int E, int n) {
    int e = blockIdx.x * 256 + threadIdx.x;
    if (e < E) {
        int dst = ei[E + e];
        int src = ei[e];
        if (dst < 0 || dst >= n) return;
        if (src < 0) src = 0;
        if (src >= n) src = n - 1;
        int slot = atomicAdd(&cursor[dst], 1);
        int2 p;
        p.x = src;
        p.y = __float_as_int(ew[e]);
        csr[slot] = p;
    }
}

// ---------------- aggregation: mean_i = (1/cnt) * sum_j w_ij * x_j ----------------
// one wave per node; lane owns dims 2l,2l+1. 4x unrolled -> 4 row-gathers in flight.
__global__ void k_agg(const float* __restrict__ X, const int* __restrict__ rowptr,
                      const int2* __restrict__ csr, const float* __restrict__ invcnt,
                      float* __restrict__ M, int n) {
    int wid = (blockIdx.x * blockDim.x + threadIdx.x) >> 6;
    int lane = threadIdx.x & 63;
    if (wid >= n) return;
    int beg = __builtin_amdgcn_readfirstlane(rowptr[wid]);
    int end = __builtin_amdgcn_readfirstlane(rowptr[wid + 1]);
    const float2* X2 = (const float2*)X;
    float ax = 0.f, ay = 0.f;
    int k = beg;
    for (; k + 4 <= end; k += 4) {
        int2 e0 = csr[k], e1 = csr[k + 1], e2 = csr[k + 2], e3 = csr[k + 3];
        float2 v0 = X2[(size_t)e0.x * 64 + lane];
        float2 v1 = X2[(size_t)e1.x * 64 + lane];
        float2 v2 = X2[(size_t)e2.x * 64 + lane];
        float2 v3 = X2[(size_t)e3.x * 64 + lane];
        float w0 = __int_as_float(e0.y), w1 = __int_as_float(e1.y);
        float w2 = __int_as_float(e2.y), w3 = __int_as_float(e3.y);
        ax += w0 * v0.x + w1 * v1.x + w2 * v2.x + w3 * v3.x;
        ay += w0 * v0.y + w1 * v1.y + w2 * v2.y + w3 * v3.y;
    }
    for (; k < end; ++k) {
        int2 e = csr[k];
        float w = __int_as_float(e.y);
        float2 v = X2[(size_t)e.x * 64 + lane];
        ax += w * v.x;
        ay += w * v.y;
    }
    float ic = invcnt[wid];
    float2 m;
    m.x = ax * ic;
    m.y = ay * ic;
    ((float2*)M)[(size_t)wid * 64 + lane] = m;
}

// ---------------- GEMM v2: LDS-staged W, 32 nodes/block, 256 threads ----------------
// out[i][j] = sum_k M[i][k]*Wl[j][k] + b[j] + sum_k X[i][k]*Wr[j][k]
// Wave wv owns nodes wv*8..wv*8+7; lane owns col j = lane (+64 if D_OUT=128).
// W staged in 32-k chunks: sW[j][36] (16B-aligned stride, even bank spread).
// BN_FLAG=1: BN+leakyReLU epilogue. BN_FLAG=0: D_OUT=64, fused row-L2-normalize.
template <int D_OUT, int BN_FLAG>
__global__ __launch_bounds__(256) void k_gemm2(
    const float* __restrict__ M, const float* __restrict__ X,
    const float* __restrict__ Wl, const float* __restrict__ bias,
    const float* __restrict__ Wr,
    const float* __restrict__ bng, const float* __restrict__ bnb,
    const float* __restrict__ bnm, const float* __restrict__ bnv,
    float* __restrict__ Out, int n) {
    constexpr int NJ = D_OUT / 64;
    __shared__ float sM[32 * 128];       // [node][k] — broadcast reads
    __shared__ float sX[32 * 128];
    __shared__ float sW[D_OUT * 36];     // [j][36], 32-k chunk, +4 pad (16B aligned)

    int t = threadIdx.x;
    int wv = t >> 6;
    int lane = t & 63;
    int node0 = blockIdx.x * 32;

    // stage M/X tiles: 32x128 floats = 1024 float4 / 256 threads = 4 each
    {
        const float4* M4 = (const float4*)(M + (size_t)node0 * 128);
        const float4* X4 = (const float4*)(X + (size_t)node0 * 128);
        float4* sM4 = (float4*)sM;
        float4* sX4 = (float4*)sX;
        float4 z = make_float4(0.f, 0.f, 0.f, 0.f);
#pragma unroll
        for (int r = 0; r < 4; ++r) {
            int idx = r * 256 + t;
            int row = idx >> 5;
            if (node0 + row < n) {
                sM4[idx] = M4[idx];
                sX4[idx] = X4[idx];
            } else {
                sM4[idx] = z;
                sX4[idx] = z;
            }
        }
    }

    float acc[8][NJ];
#pragma unroll
    for (int i = 0; i < 8; ++i)
#pragma unroll
        for (int jj = 0; jj < NJ; ++jj) acc[i][jj] = 0.f;

    // 8 stages: 0-3 = Wl chunks vs sM, 4-7 = Wr chunks vs sX
#pragma unroll 1
    for (int st = 0; st < 8; ++st) {
        const float* Wsrc = (st < 4) ? Wl : Wr;
        const float* sA = (st < 4) ? sM : sX;
        int kc = (st & 3) * 32;
        __syncthreads();
        // stage W chunk: D_OUT rows x 32 k = D_OUT*8 float4 / 256 thr
        {
            const float4* W4 = (const float4*)Wsrc;
            int kc4 = (st & 3) * 8;
#pragma unroll
            for (int r = 0; r < D_OUT / 32; ++r) {
                int idx = r * 256 + t;
                int j = idx >> 3;
                int k4 = idx & 7;
                float4 w = W4[(size_t)j * 32 + kc4 + k4];
                *(float4*)&sW[j * 36 + k4 * 4] = w;
            }
        }
        __syncthreads();
        // compute segment: 32 k values
#pragma unroll
        for (int k4 = 0; k4 < 8; ++k4) {
            float4 w[NJ];
#pragma unroll
            for (int jj = 0; jj < NJ; ++jj)
                w[jj] = *(const float4*)&sW[(lane + jj * 64) * 36 + k4 * 4];
#pragma unroll
            for (int i = 0; i < 8; ++i) {
                float4 a = *(const float4*)&sA[(wv * 8 + i) * 128 + kc + k4 * 4];
#pragma unroll
                for (int jj = 0; jj < NJ; ++jj) {
                    acc[i][jj] += a.x * w[jj].x + a.y * w[jj].y + a.z * w[jj].z +
                                  a.w * w[jj].w;
                }
            }
        }
    }

    // epilogue
    if constexpr (BN_FLAG) {
#pragma unroll
        for (int jj = 0; jj < NJ; ++jj) {
            int j = lane + jj * 64;
            float bj = bias[j];
            float g = bng[j], bb = bnb[j], mm = bnm[j];
            float iv = rsqrtf(bnv[j] + BN_EPS);
#pragma unroll
            for (int i = 0; i < 8; ++i) {
                int node = node0 + wv * 8 + i;
                float h = acc[i][jj] + bj;
                h = (h - mm) * (g * iv) + bb;
                h = h >= 0.f ? h : 0.1f * h;
                if (node < n) Out[(size_t)node * D_OUT + j] = h;
            }
        }
    } else {
        // D_OUT == 64: row L2-normalize within the wave
        float bj = bias[lane];
#pragma unroll
        for (int i = 0; i < 8; ++i) {
            float h = acc[i][0] + bj;
            float ss = h * h;
#pragma unroll
            for (int o = 32; o >= 1; o >>= 1) ss += __shfl_xor(ss, o, 64);
            float sc = 1.0f / fmaxf(sqrtf(ss), 1e-12f);
            int node = node0 + wv * 8 + i;
            if (node < n) Out[(size_t)node * 64 + lane] = h * sc;
        }
    }
}

// ---------------- launch ----------------

extern "C" void kernel_launch(void* const* d_in, const int* in_sizes, int n_in,
                              void* d_out, int out_size, void* d_ws, size_t ws_size,
                              hipStream_t stream) {
    const float* x = (const float*)d_in[0];
    const int* ei = (const int*)d_in[1];  // int32 staging
    const float* ew = (const float*)d_in[2];
    const float* W1l = (const float*)d_in[3];
    const float* b1 = (const float*)d_in[4];
    const float* W1r = (const float*)d_in[5];
    const float* W2l = (const float*)d_in[6];
    const float* b2 = (const float*)d_in[7];
    const float* W2r = (const float*)d_in[8];
    const float* W3l = (const float*)d_in[9];
    const float* b3 = (const float*)d_in[10];
    const float* W3r = (const float*)d_in[11];
    const float* bn1_g = (const float*)d_in[12];
    const float* bn1_b = (const float*)d_in[13];
    const float* bn1_m = (const float*)d_in[14];
    const float* bn1_v = (const float*)d_in[15];
    const float* bn2_g = (const float*)d_in[16];
    const float* bn2_b = (const float*)d_in[17];
    const float* bn2_m = (const float*)d_in[18];
    const float* bn2_v = (const float*)d_in[19];

    const int N = in_sizes[0] / IN_D;  // 50000
    const int E = in_sizes[2];         // 800000
    float* out = (float*)d_out;

    char* p = (char*)d_ws;
    auto alloc = [&](size_t bytes) -> void* {
        void* r = (void*)p;
        p += (bytes + 255) & ~(size_t)255;
        return r;
    };
    int* deg = (int*)alloc((size_t)N * 4);
    int* rowptr = (int*)alloc((size_t)(N + 1) * 4);
    int* cursor = (int*)alloc((size_t)N * 4);
    float* invcnt = (float*)alloc((size_t)N * 4);
    int* bsum = (int*)alloc(256 * 4);
    int2* csr = (int2*)alloc((size_t)E * 8);
    float* Mbuf = (float*)alloc((size_t)N * 128 * 4);
    float* H1 = (float*)alloc((size_t)N * 128 * 4);
    float* H2 = (float*)alloc((size_t)N * 128 * 4);

    const int NB = (N + 255) / 256;
    const int EB = (E + 255) / 256;
    const int AGG_B = (N + 3) / 4;        // 4 waves (nodes) per 256-thread block
    const int GEMM_B = (N + 31) / 32;     // 32 nodes per 256-thread block

    // --- CSR build ---
    hipMemsetAsync(deg, 0, (size_t)N * 4, stream);
    k_hist<<<EB, 256, 0, stream>>>(ei, deg, E, N);
    k_block_sum<<<NB, 256, 0, stream>>>(deg, bsum, N);
    k_scan_bsum<<<1, 256, 0, stream>>>(bsum, NB);
    k_scan_deg<<<NB, 256, 0, stream>>>(deg, bsum, rowptr, cursor, invcnt, N);
    k_fill<<<EB, 256, 0, stream>>>(ei, ew, cursor, csr, E, N);

    // --- layer 1 ---
    k_agg<<<AGG_B, 256, 0, stream>>>(x, rowptr, csr, invcnt, Mbuf, N);
    k_gemm2<128, 1><<<GEMM_B, 256, 0, stream>>>(Mbuf, x, W1l, b1, W1r, bn1_g, bn1_b,
                                                bn1_m, bn1_v, H1, N);
    // --- layer 2 ---
    k_agg<<<AGG_B, 256, 0, stream>>>(H1, rowptr, csr, invcnt, Mbuf, N);
    k_gemm2<128, 1><<<GEMM_B, 256, 0, stream>>>(Mbuf, H1, W2l, b2, W2r, bn2_g, bn2_b,
                                                bn2_m, bn2_v, H2, N);
    // --- layer 3 (+ fused L2 normalize) ---
    k_agg<<<AGG_B, 256, 0, stream>>>(H2, rowptr, csr, invcnt, Mbuf, N);
    k_gemm2<64, 0><<<GEMM_B, 256, 0, stream>>>(Mbuf, H2, W3l, b3, W3r, nullptr, nullptr,
                                               nullptr, nullptr, out, N);
}